// Round 1
// baseline (614.368 us; speedup 1.0000x reference)
//
#include <hip/hip_runtime.h>
#include <hip/hip_bf16.h>

typedef __attribute__((ext_vector_type(8))) short bf16x8;
typedef __attribute__((ext_vector_type(4))) float f32x4;
typedef unsigned short ushort_t;

#define HID 2048
#define QKVN 6144
#define SEQ 2048
#define NH 16
#define HD 128

__device__ __forceinline__ ushort_t f2b(float f) {
    union { float f; unsigned int u; } x; x.f = f;
    unsigned int r = x.u + 0x7fffu + ((x.u >> 16) & 1u);  // RNE
    return (ushort_t)(r >> 16);
}

// ---------------- cast fp32 -> bf16 (vectorized) ----------------
__global__ __launch_bounds__(256) void castbf(const float* __restrict__ in,
                                              ushort_t* __restrict__ out, int n) {
    int i = (blockIdx.x * 256 + threadIdx.x) * 8;
    if (i >= n) return;
    float4 a = *(const float4*)(in + i);
    float4 b = *(const float4*)(in + i + 4);
    union { ushort_t u[8]; uint4 v; } r;
    r.u[0] = f2b(a.x); r.u[1] = f2b(a.y); r.u[2] = f2b(a.z); r.u[3] = f2b(a.w);
    r.u[4] = f2b(b.x); r.u[5] = f2b(b.y); r.u[6] = f2b(b.z); r.u[7] = f2b(b.w);
    *(uint4*)(out + i) = r.v;
}

// ------------- transpose + cast: fp32 K x N  ->  bf16 N x K -------------
__global__ __launch_bounds__(256) void transcast(const float* __restrict__ in,
                                                 ushort_t* __restrict__ out,
                                                 int Kd, int Nd) {
    __shared__ float tile[32][33];
    int tx = threadIdx.x & 31, ty = threadIdx.x >> 5;   // ty: 0..7
    int n0 = blockIdx.x * 32, k0 = blockIdx.y * 32;
    for (int j = 0; j < 4; j++)
        tile[ty + 8 * j][tx] = in[(size_t)(k0 + ty + 8 * j) * Nd + n0 + tx];
    __syncthreads();
    for (int j = 0; j < 4; j++)
        out[(size_t)(n0 + ty + 8 * j) * Kd + k0 + tx] = f2b(tile[tx][ty + 8 * j]);
}

// ------------- transpose V region of qkv (bf16) -> vT[b][h][d][s] -------------
__global__ __launch_bounds__(256) void transV(const ushort_t* __restrict__ qkvb,
                                              ushort_t* __restrict__ vT) {
    __shared__ ushort_t tile[32][33];
    int tx = threadIdx.x & 31, ty = threadIdx.x >> 5;
    int s0 = blockIdx.x * 32, d0 = blockIdx.y * 32;
    int bh = blockIdx.z; int b = bh >> 4, h = bh & 15;
    for (int j = 0; j < 4; j++)
        tile[ty + 8 * j][tx] =
            qkvb[(size_t)(b * SEQ + s0 + ty + 8 * j) * QKVN + 2 * HID + h * HD + d0 + tx];
    __syncthreads();
    for (int j = 0; j < 4; j++)
        vT[((size_t)bh * HD + d0 + ty + 8 * j) * SEQ + s0 + tx] = tile[tx][ty + 8 * j];
}

// ------------- GEMM: C(MxN) = A(MxK,bf16) * BT(NxK,bf16)^T -------------
// 256 threads = 4 waves (2x2), 128x128 tile, BK=32, 16x16x32 MFMA.
template <bool OUT_BF16>
__global__ __launch_bounds__(256) void gemm_bt(const ushort_t* __restrict__ A,
                                               const ushort_t* __restrict__ BT,
                                               void* __restrict__ C,
                                               int M, int N, int K,
                                               int scale_cols, float scale) {
    __shared__ ushort_t As[128 * 32];
    __shared__ ushort_t Bs[128 * 32];
    const int t = threadIdx.x;
    const int l = t & 63, w = t >> 6;
    const int wm = w >> 1, wn = w & 1;
    const int m0 = blockIdx.y * 128, n0 = blockIdx.x * 128;
    const int r1 = t >> 2, ko = (t & 3) * 8;

    f32x4 acc[4][4] = {};

    for (int k0 = 0; k0 < K; k0 += 32) {
        *(uint4*)&As[(size_t)t * 8]         = *(const uint4*)(A  + (size_t)(m0 + r1) * K + k0 + ko);
        *(uint4*)&As[((size_t)t + 256) * 8] = *(const uint4*)(A  + (size_t)(m0 + 64 + r1) * K + k0 + ko);
        *(uint4*)&Bs[(size_t)t * 8]         = *(const uint4*)(BT + (size_t)(n0 + r1) * K + k0 + ko);
        *(uint4*)&Bs[((size_t)t + 256) * 8] = *(const uint4*)(BT + (size_t)(n0 + 64 + r1) * K + k0 + ko);
        __syncthreads();

        bf16x8 af[4], bf[4];
#pragma unroll
        for (int i = 0; i < 4; i++) {
            af[i] = *(const bf16x8*)&As[(wm * 64 + i * 16 + (l & 15)) * 32 + (l >> 4) * 8];
            bf[i] = *(const bf16x8*)&Bs[(wn * 64 + i * 16 + (l & 15)) * 32 + (l >> 4) * 8];
        }
#pragma unroll
        for (int mi = 0; mi < 4; mi++)
#pragma unroll
            for (int ni = 0; ni < 4; ni++)
                acc[mi][ni] = __builtin_amdgcn_mfma_f32_16x16x32_bf16(af[mi], bf[ni], acc[mi][ni], 0, 0, 0);
        __syncthreads();
    }

#pragma unroll
    for (int mi = 0; mi < 4; mi++) {
#pragma unroll
        for (int ni = 0; ni < 4; ni++) {
            int row = m0 + wm * 64 + mi * 16 + ((l >> 4) << 2);
            int col = n0 + wn * 64 + ni * 16 + (l & 15);
            float sc = (col < scale_cols) ? scale : 1.0f;
#pragma unroll
            for (int j = 0; j < 4; j++) {
                float v = acc[mi][ni][j] * sc;
                if (OUT_BF16)
                    ((ushort_t*)C)[(size_t)(row + j) * N + col] = f2b(v);
                else
                    ((float*)C)[(size_t)(row + j) * N + col] = v;
            }
        }
    }
}

// ------------- flash attention: 1 wave per (b, h, 16 q-rows) -------------
__global__ __launch_bounds__(64) void attn_fwd(const ushort_t* __restrict__ qkvb,
                                               const ushort_t* __restrict__ vT,
                                               ushort_t* __restrict__ attnb) {
    __shared__ ushort_t plds[16 * 32];
    const int l = threadIdx.x;
    const int bid = blockIdx.x;
    const int qt = bid & 127, h = (bid >> 7) & 15, b = bid >> 11;
    const int q0 = qt * 16;
    const int lr = l & 15, lg = l >> 4;  // lane row/col piece, k-group

    // Q fragments: 16 rows x 128 d, already scaled by 1/sqrt(128) in GEMM epilogue
    bf16x8 qf[4];
    const ushort_t* qbase = qkvb + (size_t)(b * SEQ + q0 + lr) * QKVN + h * HD + lg * 8;
#pragma unroll
    for (int kc = 0; kc < 4; kc++) qf[kc] = *(const bf16x8*)(qbase + kc * 32);

    f32x4 o[8] = {};
    float m[4] = {-3e38f, -3e38f, -3e38f, -3e38f};
    float ls[4] = {0.f, 0.f, 0.f, 0.f};

    const int ntiles = (q0 + 16 + 31) / 32;
    const ushort_t* kbase = qkvb + (size_t)(b * SEQ) * QKVN + HID + h * HD + lg * 8;
    const ushort_t* vbase = vT + (size_t)((b * NH + h) * HD + lr) * SEQ + lg * 8;

    for (int kt = 0; kt < ntiles; kt++) {
        const int kv0 = kt * 32;
        f32x4 s[2];
#pragma unroll
        for (int half = 0; half < 2; half++) {
            f32x4 sa = {0.f, 0.f, 0.f, 0.f};
            const ushort_t* kb = kbase + (size_t)(kv0 + half * 16 + lr) * QKVN;
#pragma unroll
            for (int kc = 0; kc < 4; kc++)
                sa = __builtin_amdgcn_mfma_f32_16x16x32_bf16(qf[kc], *(const bf16x8*)(kb + kc * 32), sa, 0, 0, 0);
            s[half] = sa;
        }

        float fac[4];
#pragma unroll
        for (int j = 0; j < 4; j++) {
            int qpos = q0 + (lg << 2) + j;
            int kp0 = kv0 + lr;
            float s0 = (kp0 <= qpos) ? s[0][j] : -3e38f;
            float s1 = (kp0 + 16 <= qpos) ? s[1][j] : -3e38f;
            float tm = fmaxf(s0, s1);
#pragma unroll
            for (int mk = 1; mk < 16; mk <<= 1) tm = fmaxf(tm, __shfl_xor(tm, mk, 64));
            float mn = fmaxf(m[j], tm);
            fac[j] = exp2f((m[j] - mn) * 1.44269504f);
            m[j] = mn;
            float p0 = exp2f((s0 - mn) * 1.44269504f);
            float p1 = exp2f((s1 - mn) * 1.44269504f);
            ls[j] = ls[j] * fac[j] + p0 + p1;
            plds[((lg << 2) + j) * 32 + lr] = f2b(p0);
            plds[((lg << 2) + j) * 32 + 16 + lr] = f2b(p1);
        }
#pragma unroll
        for (int nf = 0; nf < 8; nf++) {
#pragma unroll
            for (int j = 0; j < 4; j++) o[nf][j] *= fac[j];
        }
        __syncthreads();  // single wave: forces lgkmcnt drain before transposed read

        bf16x8 pa = *(const bf16x8*)&plds[lr * 32 + lg * 8];
        const ushort_t* vb = vbase + kv0;
#pragma unroll
        for (int nf = 0; nf < 8; nf++)
            o[nf] = __builtin_amdgcn_mfma_f32_16x16x32_bf16(pa, *(const bf16x8*)(vb + (size_t)nf * 16 * SEQ), o[nf], 0, 0, 0);
    }

#pragma unroll
    for (int j = 0; j < 4; j++) {
        float sum = ls[j];
#pragma unroll
        for (int mk = 1; mk < 16; mk <<= 1) sum += __shfl_xor(sum, mk, 64);
        ls[j] = 1.0f / sum;
    }

    ushort_t* ob = attnb + (size_t)(b * SEQ + q0) * HID + h * HD;
#pragma unroll
    for (int nf = 0; nf < 8; nf++)
#pragma unroll
        for (int j = 0; j < 4; j++)
            ob[(size_t)((lg << 2) + j) * HID + nf * 16 + lr] = f2b(o[nf][j] * ls[j]);
}

extern "C" void kernel_launch(void* const* d_in, const int* in_sizes, int n_in,
                              void* d_out, int out_size, void* d_ws, size_t ws_size,
                              hipStream_t stream) {
    const float* x     = (const float*)d_in[0];
    const float* w_qkv = (const float*)d_in[1];
    const float* w_out = (const float*)d_in[2];
    float* out = (float*)d_out;

    char* ws = (char*)d_ws;
    ushort_t* xb    = (ushort_t*)(ws);                 // 4096x2048 bf16   (16.78 MB)
    ushort_t* wqkvT = (ushort_t*)(ws + 16777216);      // 6144x2048 bf16   (25.17 MB)
    ushort_t* woutT = (ushort_t*)(ws + 41943040);      // 2048x2048 bf16   ( 8.39 MB)
    ushort_t* qkvb  = (ushort_t*)(ws + 50331648);      // 4096x6144 bf16   (50.33 MB)
    ushort_t* vT    = (ushort_t*)(ws + 100663296);     // 2*16*128*2048    (16.78 MB)
    ushort_t* attnb = (ushort_t*)(ws + 117440512);     // 4096x2048 bf16   (16.78 MB)

    const int M = 2 * SEQ;  // 4096

    castbf<<<(M * HID) / (256 * 8), 256, 0, stream>>>(x, xb, M * HID);
    transcast<<<dim3(QKVN / 32, HID / 32), 256, 0, stream>>>(w_qkv, wqkvT, HID, QKVN);
    transcast<<<dim3(HID / 32, HID / 32), 256, 0, stream>>>(w_out, woutT, HID, HID);

    // qkv = x @ w_qkv, Q columns pre-scaled by 1/sqrt(HD)
    gemm_bt<true><<<dim3(QKVN / 128, M / 128), 256, 0, stream>>>(
        xb, wqkvT, qkvb, M, QKVN, HID, HID, 0.08838834764831845f);

    transV<<<dim3(SEQ / 32, HD / 32, 2 * NH), 256, 0, stream>>>(qkvb, vT);

    attn_fwd<<<2 * NH * (SEQ / 16), 64, 0, stream>>>(qkvb, vT, attnb);

    gemm_bt<false><<<dim3(HID / 128, M / 128), 256, 0, stream>>>(
        attnb, woutT, out, M, HID, HID, 0, 1.0f);
}

// Round 2
// 486.884 us; speedup vs baseline: 1.2618x; 1.2618x over previous
//
#include <hip/hip_runtime.h>
#include <hip/hip_bf16.h>

typedef __attribute__((ext_vector_type(8))) short bf16x8;
typedef __attribute__((ext_vector_type(4))) float f32x4;
typedef unsigned short ushort_t;

#define HID 2048
#define QKVN 6144
#define SEQ 2048
#define NH 16
#define HD 128
#define QB 128
#define KVB 64

#define GLOBAL_AS __attribute__((address_space(1)))
#define LDS_AS __attribute__((address_space(3)))

__device__ __forceinline__ void gload_lds16(const ushort_t* g, ushort_t* l) {
    __builtin_amdgcn_global_load_lds((const GLOBAL_AS unsigned int*)g,
                                     (LDS_AS unsigned int*)l, 16, 0, 0);
}

__device__ __forceinline__ ushort_t f2b(float f) {
    union { float f; unsigned int u; } x; x.f = f;
    unsigned int r = x.u + 0x7fffu + ((x.u >> 16) & 1u);  // RNE
    return (ushort_t)(r >> 16);
}

// ---------------- cast fp32 -> bf16 (vectorized) ----------------
__global__ __launch_bounds__(256) void castbf(const float* __restrict__ in,
                                              ushort_t* __restrict__ out, int n) {
    int i = (blockIdx.x * 256 + threadIdx.x) * 8;
    if (i >= n) return;
    float4 a = *(const float4*)(in + i);
    float4 b = *(const float4*)(in + i + 4);
    union { ushort_t u[8]; uint4 v; } r;
    r.u[0] = f2b(a.x); r.u[1] = f2b(a.y); r.u[2] = f2b(a.z); r.u[3] = f2b(a.w);
    r.u[4] = f2b(b.x); r.u[5] = f2b(b.y); r.u[6] = f2b(b.z); r.u[7] = f2b(b.w);
    *(uint4*)(out + i) = r.v;
}

// ------------- transpose + cast: fp32 K x N  ->  bf16 N x K -------------
__global__ __launch_bounds__(256) void transcast(const float* __restrict__ in,
                                                 ushort_t* __restrict__ out,
                                                 int Kd, int Nd) {
    __shared__ float tile[32][33];
    int tx = threadIdx.x & 31, ty = threadIdx.x >> 5;
    int n0 = blockIdx.x * 32, k0 = blockIdx.y * 32;
    for (int j = 0; j < 4; j++)
        tile[ty + 8 * j][tx] = in[(size_t)(k0 + ty + 8 * j) * Nd + n0 + tx];
    __syncthreads();
    for (int j = 0; j < 4; j++)
        out[(size_t)(n0 + ty + 8 * j) * Kd + k0 + tx] = f2b(tile[tx][ty + 8 * j]);
}

// ------------- transpose V region of qkv (bf16) -> vT[b][h][d][s] -------------
__global__ __launch_bounds__(256) void transV(const ushort_t* __restrict__ qkvb,
                                              ushort_t* __restrict__ vT) {
    __shared__ ushort_t tile[32][33];
    int tx = threadIdx.x & 31, ty = threadIdx.x >> 5;
    int s0 = blockIdx.x * 32, d0 = blockIdx.y * 32;
    int bh = blockIdx.z; int b = bh >> 4, h = bh & 15;
    for (int j = 0; j < 4; j++)
        tile[ty + 8 * j][tx] =
            qkvb[(size_t)(b * SEQ + s0 + ty + 8 * j) * QKVN + 2 * HID + h * HD + d0 + tx];
    __syncthreads();
    for (int j = 0; j < 4; j++)
        vT[((size_t)bh * HD + d0 + ty + 8 * j) * SEQ + s0 + tx] = tile[tx][ty + 8 * j];
}

// ------------- GEMM: C(MxN) = A(MxK,bf16) * BT(NxK,bf16)^T -------------
// 256 threads = 4 waves (2x2), 128x128 tile, BK=32, 16x16x32 MFMA.
// Staging via global_load_lds width=16 (m97 recipe; LDS dest linear in lane order).
template <bool OUT_BF16>
__global__ __launch_bounds__(256) void gemm_bt(const ushort_t* __restrict__ A,
                                               const ushort_t* __restrict__ BT,
                                               void* __restrict__ C,
                                               int M, int N, int K,
                                               int scale_cols, float scale) {
    __shared__ __align__(16) ushort_t As[128 * 32];
    __shared__ __align__(16) ushort_t Bs[128 * 32];
    const int t = threadIdx.x;
    const int l = t & 63, w = t >> 6;
    const int wm = w >> 1, wn = w & 1;
    const int m0 = blockIdx.y * 128, n0 = blockIdx.x * 128;
    const int r1 = t >> 2, ko = (t & 3) * 8;

    f32x4 acc[4][4] = {};

    for (int k0 = 0; k0 < K; k0 += 32) {
        gload_lds16(A + (size_t)(m0 + r1) * K + k0 + ko,      &As[(size_t)t * 8]);
        gload_lds16(A + (size_t)(m0 + 64 + r1) * K + k0 + ko, &As[((size_t)t + 256) * 8]);
        gload_lds16(BT + (size_t)(n0 + r1) * K + k0 + ko,     &Bs[(size_t)t * 8]);
        gload_lds16(BT + (size_t)(n0 + 64 + r1) * K + k0 + ko,&Bs[((size_t)t + 256) * 8]);
        __syncthreads();

        bf16x8 af[4], bfr[4];
#pragma unroll
        for (int i = 0; i < 4; i++) {
            af[i]  = *(const bf16x8*)&As[(wm * 64 + i * 16 + (l & 15)) * 32 + (l >> 4) * 8];
            bfr[i] = *(const bf16x8*)&Bs[(wn * 64 + i * 16 + (l & 15)) * 32 + (l >> 4) * 8];
        }
#pragma unroll
        for (int mi = 0; mi < 4; mi++)
#pragma unroll
            for (int ni = 0; ni < 4; ni++)
                acc[mi][ni] = __builtin_amdgcn_mfma_f32_16x16x32_bf16(af[mi], bfr[ni], acc[mi][ni], 0, 0, 0);
        __syncthreads();
    }

#pragma unroll
    for (int mi = 0; mi < 4; mi++) {
#pragma unroll
        for (int ni = 0; ni < 4; ni++) {
            int row = m0 + wm * 64 + mi * 16 + ((l >> 4) << 2);
            int col = n0 + wn * 64 + ni * 16 + (l & 15);
            float sc = (col < scale_cols) ? scale : 1.0f;
#pragma unroll
            for (int j = 0; j < 4; j++) {
                float v = acc[mi][ni][j] * sc;
                if (OUT_BF16)
                    ((ushort_t*)C)[(size_t)(row + j) * N + col] = f2b(v);
                else
                    ((float*)C)[(size_t)(row + j) * N + col] = v;
            }
        }
    }
}

// ------------- flash attention v2: 4 waves x 32 q-rows, KVB=64, LDS-staged K/V -------------
__global__ __launch_bounds__(256) void attn_fwd2(const ushort_t* __restrict__ qkvb,
                                                 const ushort_t* __restrict__ vT,
                                                 ushort_t* __restrict__ attnb) {
    __shared__ __align__(16) ushort_t Ks[64 * 128];   // [kv][d], swizzled, 16 KB
    __shared__ __align__(16) ushort_t Vs[128 * 64];   // [d][kv], swizzled, 16 KB
    __shared__ __align__(16) ushort_t Ps[4][32 * 64]; // per-wave P, swizzled, 16 KB

    const int t = threadIdx.x;
    const int l = t & 63, w = t >> 6;
    const int lr = l & 15, lg = l >> 4;
    const int q0 = blockIdx.x * QB;
    const int h = blockIdx.y, b = blockIdx.z;
    const int q0w = q0 + w * 32;

    // Q fragments: 2 m-frags x 4 k-chunks (Q pre-scaled by 1/sqrt(HD) in GEMM)
    bf16x8 qf[2][4];
#pragma unroll
    for (int mf = 0; mf < 2; mf++) {
        const ushort_t* qb = qkvb + (size_t)(b * SEQ + q0w + mf * 16 + lr) * QKVN + h * HD + lg * 8;
#pragma unroll
        for (int kc = 0; kc < 4; kc++) qf[mf][kc] = *(const bf16x8*)(qb + kc * 32);
    }

    f32x4 o[2][8] = {};
    float m[2][4], ls[2][4];
#pragma unroll
    for (int mf = 0; mf < 2; mf++)
#pragma unroll
        for (int j = 0; j < 4; j++) { m[mf][j] = -3e38f; ls[mf][j] = 0.f; }

    const int NT = (q0 + QB) / KVB;
    const ushort_t* kg = qkvb + (size_t)(b * SEQ) * QKVN + HID + h * HD;
    const ushort_t* vg = vT + (size_t)(b * NH + h) * HD * SEQ;

    char* KsB = (char*)Ks;
    char* VsB = (char*)Vs;
    char* PsB = (char*)Ps[w];

    const int krow = t >> 2, kc0 = t & 3;   // K stage: row 0..63, 4 x 16B chunks
    const int vrow = t >> 1, vc0 = t & 1;   // V stage: row 0..127, 4 x 16B chunks
    const int kswz = (krow & 7) << 4;
    const int vswz = (vrow & 7) << 4;
    const int psz = (lr & 7) << 4;          // swizzle for reads at row ? lr (mod 8 == lr&7)

    for (int kt = 0; kt < NT; kt++) {
        const int kv0 = kt * KVB;
        __syncthreads();  // protect previous tile's readers from new writes
        {
            const ushort_t* kr = kg + (size_t)(kv0 + krow) * QKVN;
#pragma unroll
            for (int i = 0; i < 4; i++) {
                int cb = (kc0 + 4 * i) * 16;
                *(uint4*)(KsB + krow * 256 + (cb ^ kswz)) = *(const uint4*)(kr + (cb >> 1));
            }
            const ushort_t* vr = vg + (size_t)vrow * SEQ + kv0;
#pragma unroll
            for (int i = 0; i < 4; i++) {
                int cb = (vc0 + 2 * i) * 16;
                *(uint4*)(VsB + vrow * 128 + (cb ^ vswz)) = *(const uint4*)(vr + (cb >> 1));
            }
        }
        __syncthreads();

        if (kv0 >= q0w + 32) continue;  // causal: this wave doesn't need this tile

        // ---- QK^T: S[2 mf][4 nf] over 64 kv ----
        f32x4 s[2][4];
#pragma unroll
        for (int nf = 0; nf < 4; nf++) {
            const int r = nf * 16 + lr;
            s[0][nf] = (f32x4){0.f, 0.f, 0.f, 0.f};
            s[1][nf] = (f32x4){0.f, 0.f, 0.f, 0.f};
#pragma unroll
            for (int kc = 0; kc < 4; kc++) {
                bf16x8 kf = *(const bf16x8*)(KsB + r * 256 + ((kc * 64 + lg * 16) ^ psz));
                s[0][nf] = __builtin_amdgcn_mfma_f32_16x16x32_bf16(qf[0][kc], kf, s[0][nf], 0, 0, 0);
                s[1][nf] = __builtin_amdgcn_mfma_f32_16x16x32_bf16(qf[1][kc], kf, s[1][nf], 0, 0, 0);
            }
        }

        const bool diag = (kv0 + KVB - 1 > q0w);  // boundary tile -> needs masking
#pragma unroll
        for (int mf = 0; mf < 2; mf++) {
            float fac[4];
#pragma unroll
            for (int j = 0; j < 4; j++) {
                const int qpos = q0w + mf * 16 + lg * 4 + j;
                if (diag) {
#pragma unroll
                    for (int nf = 0; nf < 4; nf++)
                        if (kv0 + nf * 16 + lr > qpos) s[mf][nf][j] = -3e38f;
                }
                float tm = fmaxf(fmaxf(s[mf][0][j], s[mf][1][j]), fmaxf(s[mf][2][j], s[mf][3][j]));
#pragma unroll
                for (int mk = 1; mk < 16; mk <<= 1) tm = fmaxf(tm, __shfl_xor(tm, mk, 64));
                const float mn = fmaxf(m[mf][j], tm);
                fac[j] = exp2f((m[mf][j] - mn) * 1.44269504f);
                m[mf][j] = mn;
                const int row = mf * 16 + lg * 4 + j;
                const int rsz = (row & 7) << 4;
                float psum = 0.f;
#pragma unroll
                for (int nf = 0; nf < 4; nf++) {
                    float p = exp2f((s[mf][nf][j] - mn) * 1.44269504f);
                    psum += p;
                    *(ushort_t*)(PsB + row * 128 + ((nf * 32 + lr * 2) ^ rsz)) = f2b(p);
                }
                ls[mf][j] = ls[mf][j] * fac[j] + psum;
            }
#pragma unroll
            for (int nf2 = 0; nf2 < 8; nf2++)
#pragma unroll
                for (int j = 0; j < 4; j++) o[mf][nf2][j] *= fac[j];
        }

        // ---- PV: O += P(32x64) @ V(64x128) ----
#pragma unroll
        for (int mf = 0; mf < 2; mf++) {
            const int r = mf * 16 + lr;
            bf16x8 pa0 = *(const bf16x8*)(PsB + r * 128 + ((lg * 16) ^ psz));
            bf16x8 pa1 = *(const bf16x8*)(PsB + r * 128 + ((64 + lg * 16) ^ psz));
#pragma unroll
            for (int nf2 = 0; nf2 < 8; nf2++) {
                const int vr2 = nf2 * 16 + lr;
                bf16x8 vb0 = *(const bf16x8*)(VsB + vr2 * 128 + ((lg * 16) ^ psz));
                bf16x8 vb1 = *(const bf16x8*)(VsB + vr2 * 128 + ((64 + lg * 16) ^ psz));
                o[mf][nf2] = __builtin_amdgcn_mfma_f32_16x16x32_bf16(pa0, vb0, o[mf][nf2], 0, 0, 0);
                o[mf][nf2] = __builtin_amdgcn_mfma_f32_16x16x32_bf16(pa1, vb1, o[mf][nf2], 0, 0, 0);
            }
        }
    }

    // ---- epilogue: normalize and store ----
#pragma unroll
    for (int mf = 0; mf < 2; mf++)
#pragma unroll
        for (int j = 0; j < 4; j++) {
            float sum = ls[mf][j];
#pragma unroll
            for (int mk = 1; mk < 16; mk <<= 1) sum += __shfl_xor(sum, mk, 64);
            ls[mf][j] = 1.0f / sum;
        }
    ushort_t* ob = attnb + (size_t)(b * SEQ + q0w) * HID + h * HD;
#pragma unroll
    for (int mf = 0; mf < 2; mf++)
#pragma unroll
        for (int nf2 = 0; nf2 < 8; nf2++)
#pragma unroll
            for (int j = 0; j < 4; j++)
                ob[(size_t)(mf * 16 + lg * 4 + j) * HID + nf2 * 16 + lr] =
                    f2b(o[mf][nf2][j] * ls[mf][j]);
}

extern "C" void kernel_launch(void* const* d_in, const int* in_sizes, int n_in,
                              void* d_out, int out_size, void* d_ws, size_t ws_size,
                              hipStream_t stream) {
    const float* x     = (const float*)d_in[0];
    const float* w_qkv = (const float*)d_in[1];
    const float* w_out = (const float*)d_in[2];
    float* out = (float*)d_out;

    char* ws = (char*)d_ws;
    ushort_t* xb    = (ushort_t*)(ws);                 // 4096x2048 bf16
    ushort_t* wqkvT = (ushort_t*)(ws + 16777216);      // 6144x2048 bf16
    ushort_t* woutT = (ushort_t*)(ws + 41943040);      // 2048x2048 bf16
    ushort_t* qkvb  = (ushort_t*)(ws + 50331648);      // 4096x6144 bf16
    ushort_t* vT    = (ushort_t*)(ws + 100663296);     // [b][h][d][s] bf16
    ushort_t* attnb = (ushort_t*)(ws + 117440512);     // 4096x2048 bf16

    const int M = 2 * SEQ;  // 4096

    castbf<<<(M * HID) / (256 * 8), 256, 0, stream>>>(x, xb, M * HID);
    transcast<<<dim3(QKVN / 32, HID / 32), 256, 0, stream>>>(w_qkv, wqkvT, HID, QKVN);
    transcast<<<dim3(HID / 32, HID / 32), 256, 0, stream>>>(w_out, woutT, HID, HID);

    gemm_bt<true><<<dim3(QKVN / 128, M / 128), 256, 0, stream>>>(
        xb, wqkvT, qkvb, M, QKVN, HID, HID, 0.08838834764831845f);

    transV<<<dim3(SEQ / 32, HD / 32, 2 * NH), 256, 0, stream>>>(qkvb, vT);

    attn_fwd2<<<dim3(SEQ / QB, NH, 2), 256, 0, stream>>>(qkvb, vT, attnb);

    gemm_bt<false><<<dim3(HID / 128, M / 128), 256, 0, stream>>>(
        attnb, woutT, out, M, HID, HID, 0, 1.0f);
}

// Round 3
// 312.850 us; speedup vs baseline: 1.9638x; 1.5563x over previous
//
#include <hip/hip_runtime.h>
#include <hip/hip_bf16.h>

typedef __attribute__((ext_vector_type(8))) short bf16x8;
typedef __attribute__((ext_vector_type(4))) float f32x4;
typedef unsigned short ushort_t;

#define HID 2048
#define QKVN 6144
#define SEQ 2048
#define NH 16
#define HD 128
#define QB 128
#define KVB 64

#define GLOBAL_AS __attribute__((address_space(1)))
#define LDS_AS __attribute__((address_space(3)))

__device__ __forceinline__ void gload_lds16(const ushort_t* g, ushort_t* l) {
    __builtin_amdgcn_global_load_lds((const GLOBAL_AS unsigned int*)g,
                                     (LDS_AS unsigned int*)l, 16, 0, 0);
}

__device__ __forceinline__ ushort_t f2b(float f) {
    union { float f; unsigned int u; } x; x.f = f;
    unsigned int r = x.u + 0x7fffu + ((x.u >> 16) & 1u);  // RNE
    return (ushort_t)(r >> 16);
}

// ---------------- cast fp32 -> bf16 (vectorized) ----------------
__global__ __launch_bounds__(256) void castbf(const float* __restrict__ in,
                                              ushort_t* __restrict__ out, int n) {
    int i = (blockIdx.x * 256 + threadIdx.x) * 8;
    if (i >= n) return;
    float4 a = *(const float4*)(in + i);
    float4 b = *(const float4*)(in + i + 4);
    union { ushort_t u[8]; uint4 v; } r;
    r.u[0] = f2b(a.x); r.u[1] = f2b(a.y); r.u[2] = f2b(a.z); r.u[3] = f2b(a.w);
    r.u[4] = f2b(b.x); r.u[5] = f2b(b.y); r.u[6] = f2b(b.z); r.u[7] = f2b(b.w);
    *(uint4*)(out + i) = r.v;
}

// ------------- transpose + cast: fp32 K x N  ->  bf16 N x K -------------
__global__ __launch_bounds__(256) void transcast(const float* __restrict__ in,
                                                 ushort_t* __restrict__ out,
                                                 int Kd, int Nd) {
    __shared__ float tile[32][33];
    int tx = threadIdx.x & 31, ty = threadIdx.x >> 5;
    int n0 = blockIdx.x * 32, k0 = blockIdx.y * 32;
    for (int j = 0; j < 4; j++)
        tile[ty + 8 * j][tx] = in[(size_t)(k0 + ty + 8 * j) * Nd + n0 + tx];
    __syncthreads();
    for (int j = 0; j < 4; j++)
        out[(size_t)(n0 + ty + 8 * j) * Kd + k0 + tx] = f2b(tile[tx][ty + 8 * j]);
}

// ------------- transpose V region of qkv (bf16) -> vT[b][h][d][s] -------------
__global__ __launch_bounds__(256) void transV(const ushort_t* __restrict__ qkvb,
                                              ushort_t* __restrict__ vT) {
    __shared__ ushort_t tile[32][33];
    int tx = threadIdx.x & 31, ty = threadIdx.x >> 5;
    int s0 = blockIdx.x * 32, d0 = blockIdx.y * 32;
    int bh = blockIdx.z; int b = bh >> 4, h = bh & 15;
    for (int j = 0; j < 4; j++)
        tile[ty + 8 * j][tx] =
            qkvb[(size_t)(b * SEQ + s0 + ty + 8 * j) * QKVN + 2 * HID + h * HD + d0 + tx];
    __syncthreads();
    for (int j = 0; j < 4; j++)
        vT[((size_t)bh * HD + d0 + ty + 8 * j) * SEQ + s0 + tx] = tile[tx][ty + 8 * j];
}

// ------------- GEMM: C(MxN) = A(MxK,bf16) * BT(NxK,bf16)^T -------------
template <bool OUT_BF16>
__global__ __launch_bounds__(256) void gemm_bt(const ushort_t* __restrict__ A,
                                               const ushort_t* __restrict__ BT,
                                               void* __restrict__ C,
                                               int M, int N, int K,
                                               int scale_cols, float scale) {
    __shared__ __align__(16) ushort_t As[128 * 32];
    __shared__ __align__(16) ushort_t Bs[128 * 32];
    const int t = threadIdx.x;
    const int l = t & 63, w = t >> 6;
    const int wm = w >> 1, wn = w & 1;
    const int m0 = blockIdx.y * 128, n0 = blockIdx.x * 128;
    const int r1 = t >> 2, ko = (t & 3) * 8;

    f32x4 acc[4][4] = {};

    for (int k0 = 0; k0 < K; k0 += 32) {
        gload_lds16(A + (size_t)(m0 + r1) * K + k0 + ko,      &As[(size_t)t * 8]);
        gload_lds16(A + (size_t)(m0 + 64 + r1) * K + k0 + ko, &As[((size_t)t + 256) * 8]);
        gload_lds16(BT + (size_t)(n0 + r1) * K + k0 + ko,     &Bs[(size_t)t * 8]);
        gload_lds16(BT + (size_t)(n0 + 64 + r1) * K + k0 + ko,&Bs[((size_t)t + 256) * 8]);
        __syncthreads();

        bf16x8 af[4], bfr[4];
#pragma unroll
        for (int i = 0; i < 4; i++) {
            af[i]  = *(const bf16x8*)&As[(wm * 64 + i * 16 + (l & 15)) * 32 + (l >> 4) * 8];
            bfr[i] = *(const bf16x8*)&Bs[(wn * 64 + i * 16 + (l & 15)) * 32 + (l >> 4) * 8];
        }
#pragma unroll
        for (int mi = 0; mi < 4; mi++)
#pragma unroll
            for (int ni = 0; ni < 4; ni++)
                acc[mi][ni] = __builtin_amdgcn_mfma_f32_16x16x32_bf16(af[mi], bfr[ni], acc[mi][ni], 0, 0, 0);
        __syncthreads();
    }

#pragma unroll
    for (int mi = 0; mi < 4; mi++) {
#pragma unroll
        for (int ni = 0; ni < 4; ni++) {
            int row = m0 + wm * 64 + mi * 16 + ((l >> 4) << 2);
            int col = n0 + wn * 64 + ni * 16 + (l & 15);
            float sc = (col < scale_cols) ? scale : 1.0f;
#pragma unroll
            for (int j = 0; j < 4; j++) {
                float v = acc[mi][ni][j] * sc;
                if (OUT_BF16)
                    ((ushort_t*)C)[(size_t)(row + j) * N + col] = f2b(v);
                else
                    ((float*)C)[(size_t)(row + j) * N + col] = v;
            }
        }
    }
}

// ------------- flash attention v3: 8 waves x 16 q-rows, paired q-tiles, dbuf gload_lds -------------
__global__ __launch_bounds__(512, 1) void attn_fwd3(const ushort_t* __restrict__ qkvb,
                                                    const ushort_t* __restrict__ vT,
                                                    ushort_t* __restrict__ attnb) {
    __shared__ __align__(16) ushort_t Ks[2][64 * 128];   // [kv][d] swizzled, 16 KB each
    __shared__ __align__(16) ushort_t Vs[2][128 * 64];   // [d][kv] swizzled, 16 KB each
    __shared__ __align__(16) ushort_t Ps[8][16 * 64];    // per-wave P, 2 KB each

    const int t = threadIdx.x;
    const int l = t & 63, w = t >> 6;
    const int lr = l & 15, lg = l >> 4;
    const int pr = blockIdx.x, h = blockIdx.y, b = blockIdx.z;

    const ushort_t* kg = qkvb + (size_t)(b * SEQ) * QKVN + HID + h * HD;
    const ushort_t* vg = vT + (size_t)(b * NH + h) * HD * SEQ;

    char* PsB = (char*)Ps[w];
    const int pssz = ((lr & 7) ^ ((lr >> 3) << 1)) << 4;

    // staging constants: wave w stages K chunks {2w,2w+1}, V chunks {2w,2w+1}
    const int kcA = 2 * w, kcB = 2 * w + 1;
    const int krA = 8 * w + (l >> 4), krB = krA + 4;          // K tile rows
    const int kcolA = ((l & 15) ^ (l >> 4)) << 3;             // pre-swizzled source col (elems)
    const int kcolB = ((l & 15) ^ (4 + (l >> 4))) << 3;
    const int vrA = 16 * w + (l >> 3), vrB = vrA + 8;         // V tile rows (d)
    const int vcol = ((l & 7) ^ (l >> 3)) << 3;

    for (int seg = 0; seg < 2; seg++) {
        const int qt = (seg == 0) ? pr : 15 - pr;             // paired q-tiles: equal total work
        const int q0 = qt * QB;
        const int q0w = q0 + w * 16;
        const int NT = (q0 + QB) / KVB;

        bf16x8 qf[4];
        {
            const ushort_t* qb = qkvb + (size_t)(b * SEQ + q0w + lr) * QKVN + h * HD + lg * 8;
#pragma unroll
            for (int kc = 0; kc < 4; kc++) qf[kc] = *(const bf16x8*)(qb + kc * 32);
        }
        f32x4 o[8] = {};
        float m[4] = {-3e38f, -3e38f, -3e38f, -3e38f};
        float ls[4] = {0.f, 0.f, 0.f, 0.f};

        __syncthreads();  // all waves done with previous segment's LDS
        gload_lds16(kg + (size_t)krA * QKVN + kcolA, &Ks[0][kcA * 512 + l * 8]);
        gload_lds16(kg + (size_t)krB * QKVN + kcolB, &Ks[0][kcB * 512 + l * 8]);
        gload_lds16(vg + (size_t)vrA * SEQ + vcol,   &Vs[0][kcA * 512 + l * 8]);
        gload_lds16(vg + (size_t)vrB * SEQ + vcol,   &Vs[0][kcB * 512 + l * 8]);

        for (int kt = 0; kt < NT; kt++) {
            const int kv0 = kt * KVB;
            __syncthreads();  // implicit vmcnt(0): my staged tile is in LDS; prev readers done
            if (kt + 1 < NT) {
                const int nb = (kt + 1) & 1;
                const int nkv = kv0 + KVB;
                gload_lds16(kg + (size_t)(nkv + krA) * QKVN + kcolA, &Ks[nb][kcA * 512 + l * 8]);
                gload_lds16(kg + (size_t)(nkv + krB) * QKVN + kcolB, &Ks[nb][kcB * 512 + l * 8]);
                gload_lds16(vg + (size_t)vrA * SEQ + nkv + vcol,     &Vs[nb][kcA * 512 + l * 8]);
                gload_lds16(vg + (size_t)vrB * SEQ + nkv + vcol,     &Vs[nb][kcB * 512 + l * 8]);
            }
            if (kv0 > q0w + 15) continue;  // causal: wave doesn't need this tile
            const char* KsB = (const char*)Ks[kt & 1];
            const char* VsB = (const char*)Vs[kt & 1];

            // ---- QK^T: 16 q-rows x 64 kv ----
            f32x4 s[4];
            const int rs = (lr & 7) << 4;
#pragma unroll
            for (int nf = 0; nf < 4; nf++) {
                const int r = nf * 16 + lr;
                s[nf] = (f32x4){0.f, 0.f, 0.f, 0.f};
#pragma unroll
                for (int kc = 0; kc < 4; kc++) {
                    bf16x8 kf = *(const bf16x8*)(KsB + r * 256 + ((kc * 64 + lg * 16) ^ rs));
                    s[nf] = __builtin_amdgcn_mfma_f32_16x16x32_bf16(qf[kc], kf, s[nf], 0, 0, 0);
                }
            }

            // ---- mask + row max ----
            const bool diag = (kv0 + 63 > q0w);
            float tm[4];
#pragma unroll
            for (int j = 0; j < 4; j++) {
                if (diag) {
                    const int qpos = q0w + lg * 4 + j;
#pragma unroll
                    for (int nf = 0; nf < 4; nf++)
                        if (kv0 + nf * 16 + lr > qpos) s[nf][j] = -3e38f;
                }
                tm[j] = fmaxf(fmaxf(s[0][j], s[1][j]), fmaxf(s[2][j], s[3][j]));
#pragma unroll
                for (int mk = 1; mk < 16; mk <<= 1)
                    tm[j] = fmaxf(tm[j], __shfl_xor(tm[j], mk, 64));
            }

            // ---- defer-max (T13): rescale only when max grew > 8 ----
            float grow = fmaxf(fmaxf(tm[0] - m[0], tm[1] - m[1]),
                               fmaxf(tm[2] - m[2], tm[3] - m[3]));
            if (!__all(grow <= 8.0f)) {
#pragma unroll
                for (int j = 0; j < 4; j++) {
                    const float mn = fmaxf(m[j], tm[j]);
                    const float fac = exp2f((m[j] - mn) * 1.44269504f);
                    m[j] = mn; ls[j] *= fac;
#pragma unroll
                    for (int nf2 = 0; nf2 < 8; nf2++) o[nf2][j] *= fac;
                }
            }

            // ---- P = exp(S - m), store bf16 (trunc) to per-wave LDS ----
#pragma unroll
            for (int j = 0; j < 4; j++) {
                const int row = lg * 4 + j;
                const int rsz = ((row & 7) ^ ((row >> 3) << 1)) << 4;
                float psum = 0.f;
#pragma unroll
                for (int nf = 0; nf < 4; nf++) {
                    float p = exp2f((s[nf][j] - m[j]) * 1.44269504f);
                    psum += p;
                    union { float f; unsigned u; } cv; cv.f = p;
                    *(ushort_t*)(PsB + row * 128 + ((nf * 32 + lr * 2) ^ rsz)) = (ushort_t)(cv.u >> 16);
                }
                ls[j] += psum;
            }

            // ---- PV: O += P(16x64) @ V(64x128) ----
            bf16x8 pa0 = *(const bf16x8*)(PsB + lr * 128 + ((lg * 16) ^ pssz));
            bf16x8 pa1 = *(const bf16x8*)(PsB + lr * 128 + ((64 + lg * 16) ^ pssz));
#pragma unroll
            for (int nf2 = 0; nf2 < 8; nf2++) {
                const int vr2 = nf2 * 16 + lr;
                bf16x8 vb0 = *(const bf16x8*)(VsB + vr2 * 128 + ((lg * 16) ^ rs));
                bf16x8 vb1 = *(const bf16x8*)(VsB + vr2 * 128 + ((64 + lg * 16) ^ rs));
                o[nf2] = __builtin_amdgcn_mfma_f32_16x16x32_bf16(pa0, vb0, o[nf2], 0, 0, 0);
                o[nf2] = __builtin_amdgcn_mfma_f32_16x16x32_bf16(pa1, vb1, o[nf2], 0, 0, 0);
            }
        }

        // ---- epilogue ----
        float inv[4];
#pragma unroll
        for (int j = 0; j < 4; j++) {
            float sum = ls[j];
#pragma unroll
            for (int mk = 1; mk < 16; mk <<= 1) sum += __shfl_xor(sum, mk, 64);
            inv[j] = 1.0f / sum;
        }
        ushort_t* ob = attnb + (size_t)(b * SEQ + q0w) * HID + h * HD;
#pragma unroll
        for (int nf2 = 0; nf2 < 8; nf2++)
#pragma unroll
            for (int j = 0; j < 4; j++)
                ob[(size_t)(lg * 4 + j) * HID + nf2 * 16 + lr] = f2b(o[nf2][j] * inv[j]);
    }
}

extern "C" void kernel_launch(void* const* d_in, const int* in_sizes, int n_in,
                              void* d_out, int out_size, void* d_ws, size_t ws_size,
                              hipStream_t stream) {
    const float* x     = (const float*)d_in[0];
    const float* w_qkv = (const float*)d_in[1];
    const float* w_out = (const float*)d_in[2];
    float* out = (float*)d_out;

    char* ws = (char*)d_ws;
    ushort_t* xb    = (ushort_t*)(ws);                 // 4096x2048 bf16
    ushort_t* wqkvT = (ushort_t*)(ws + 16777216);      // 6144x2048 bf16
    ushort_t* woutT = (ushort_t*)(ws + 41943040);      // 2048x2048 bf16
    ushort_t* qkvb  = (ushort_t*)(ws + 50331648);      // 4096x6144 bf16
    ushort_t* vT    = (ushort_t*)(ws + 100663296);     // [b][h][d][s] bf16
    ushort_t* attnb = (ushort_t*)(ws + 117440512);     // 4096x2048 bf16

    const int M = 2 * SEQ;  // 4096

    castbf<<<(M * HID) / (256 * 8), 256, 0, stream>>>(x, xb, M * HID);
    transcast<<<dim3(QKVN / 32, HID / 32), 256, 0, stream>>>(w_qkv, wqkvT, HID, QKVN);
    transcast<<<dim3(HID / 32, HID / 32), 256, 0, stream>>>(w_out, woutT, HID, HID);

    gemm_bt<true><<<dim3(QKVN / 128, M / 128), 256, 0, stream>>>(
        xb, wqkvT, qkvb, M, QKVN, HID, HID, 0.08838834764831845f);

    transV<<<dim3(SEQ / 32, HD / 32, 2 * NH), 256, 0, stream>>>(qkvb, vT);

    attn_fwd3<<<dim3(8, NH, 2), 512, 0, stream>>>(qkvb, vT, attnb);

    gemm_bt<false><<<dim3(HID / 128, M / 128), 256, 0, stream>>>(
        attnb, woutT, out, M, HID, HID, 0, 1.0f);
}